// Round 5
// baseline (177.407 us; speedup 1.0000x reference)
//
#include <hip/hip_runtime.h>
#include <stdint.h>

// Problem constants (fixed-shape problem)
#define SEQ    2048
#define DMODEL 2048
#define NHEAD  32
#define NKV    8
#define HDIM   64

typedef __bf16 bf16x8 __attribute__((ext_vector_type(8)));
typedef float  f32x4  __attribute__((ext_vector_type(4)));

#define SCALE2 0.180336880f   // 0.125 * log2(e): scores land in log2 domain
#define THR2   12.0f          // defer-max threshold (log2 domain); P <= 2^12

__device__ __forceinline__ ushort bf(float f){
  __bf16 h = (__bf16)f;               // native RNE convert on gfx950
  return __builtin_bit_cast(unsigned short, h);
}

__device__ __forceinline__ void gl_lds16(const void* g, void* l){
  __builtin_amdgcn_global_load_lds(
      (const __attribute__((address_space(1))) uint32_t*)g,
      (__attribute__((address_space(3))) uint32_t*)l, 16, 0, 0);
}

// ------------- all f32->bf16 converts in one kernel -------------
// regions in float4 units: x[0,1048576) wq[.. +1048576) wk[..+262144)
// wv[..+262144) wo[..+1048576)
__global__ __launch_bounds__(256) void k_cvt_all(const float* __restrict__ x,
                                                 const float* __restrict__ wq,
                                                 const float* __restrict__ wk,
                                                 const float* __restrict__ wv,
                                                 const float* __restrict__ wo,
                                                 ushort* __restrict__ xb,
                                                 ushort* __restrict__ wcat,
                                                 ushort* __restrict__ wob){
  int i = blockIdx.x * 256 + threadIdx.x;
  const float* src; ushort* dst; int s4; int d4;
  if (i < 1048576)      { src = x;  dst = xb;   s4 = i;           d4 = s4; }
  else if (i < 2097152) { src = wq; dst = wcat; s4 = i - 1048576; d4 = s4; }
  else if (i < 2359296) { src = wk; dst = wcat; s4 = i - 2097152; d4 = s4 + 1048576; }
  else if (i < 2621440) { src = wv; dst = wcat; s4 = i - 2359296; d4 = s4 + 1310720; }
  else                  { src = wo; dst = wob;  s4 = i - 2621440; d4 = s4; }
  float4 v = reinterpret_cast<const float4*>(src)[s4];
  ushort4 o;
  o.x = bf(v.x); o.y = bf(v.y); o.z = bf(v.z); o.w = bf(v.w);
  reinterpret_cast<ushort4*>(dst)[d4] = o;
}

// ---------------- QKV GEMM with fused RMSNorm+RoPE epilogue ----------------
// A: xb [2048][2048] bf16, B: wcat [3072][2048] bf16 ("B^T" form).
// 128x128 tile, BK=64, 4 waves (2x2). Each wave's 64 cols = one 64-wide unit:
// units 0..31 = Q heads (norm+rope+SCALE2 -> qb), 32..39 = K heads
// (norm+rope -> kb), 40..47 = V heads (plain bf16 -> vb).
__global__ __launch_bounds__(256) void k_gemm_qkv(const ushort* __restrict__ A,
                                                  const ushort* __restrict__ B,
                                                  const float* __restrict__ cosp,
                                                  const float* __restrict__ sinp,
                                                  const float* __restrict__ qg,
                                                  const float* __restrict__ kg,
                                                  ushort* __restrict__ qb,
                                                  ushort* __restrict__ kb,
                                                  ushort* __restrict__ vb){
  __shared__ ushort As[128*64];
  __shared__ ushort Bs[128*64];
  const int tid = threadIdx.x, lane = tid & 63, wid = tid >> 6;
  const int bm = blockIdx.y * 128, bn = blockIdx.x * 128;
  const int wr = wid >> 1, wc = wid & 1;
  const int l15 = lane & 15, u = lane >> 4;
  const int K = 2048;

  const int srow = wid*32 + (lane >> 3);
  const int scol = ((lane & 7) ^ (lane >> 3)) * 8;   // pre-swizzled k-chunk
  const ushort* Abase = A + (size_t)(bm + srow) * K + scol;
  const ushort* Bbase = B + (size_t)(bn + srow) * K + scol;

  f32x4 acc[4][4] = {};

  for (int k0 = 0; k0 < K; k0 += 64){
    __syncthreads();
#pragma unroll
    for (int c = 0; c < 4; c++){
      gl_lds16(Abase + k0 + (size_t)c*8*K, As + (wid*32 + c*8)*64);
      gl_lds16(Bbase + k0 + (size_t)c*8*K, Bs + (wid*32 + c*8)*64);
    }
    __syncthreads();   // drains vmcnt(0)

#pragma unroll
    for (int kc = 0; kc < 2; kc++){
      bf16x8 af[4], bfr[4];
#pragma unroll
      for (int m = 0; m < 4; m++){
        int row = wr*64 + m*16 + l15;
        af[m] = *reinterpret_cast<const bf16x8*>(&As[row*64 + (((kc*4+u) ^ (row&7))*8)]);
      }
#pragma unroll
      for (int n = 0; n < 4; n++){
        int row = wc*64 + n*16 + l15;
        bfr[n] = *reinterpret_cast<const bf16x8*>(&Bs[row*64 + (((kc*4+u) ^ (row&7))*8)]);
      }
#pragma unroll
      for (int m = 0; m < 4; m++)
#pragma unroll
        for (int n = 0; n < 4; n++)
          acc[m][n] = __builtin_amdgcn_mfma_f32_16x16x32_bf16(af[m], bfr[n], acc[m][n], 0, 0, 0);
    }
  }

  // ---- fused epilogue (C/D layout: col=lane&15, row=(lane>>4)*4+j) ----
  const int unit = blockIdx.x*2 + wc;    // this wave's 64-col unit
  const int row0 = bm + wr*64;
  if (unit < 40){
    const bool isq = unit < 32;
    float g[4];
#pragma unroll
    for (int n = 0; n < 4; n++)
      g[n] = isq ? qg[n*16 + l15] * SCALE2 : kg[n*16 + l15];
    ushort* ob     = isq ? qb : kb;
    const int ostr = isq ? 2048 : 512;
    const int ocol = isq ? unit*64 : (unit-32)*64;
#pragma unroll
    for (int m = 0; m < 4; m++){
      f32x4 ss = {};
#pragma unroll
      for (int n = 0; n < 4; n++) ss += acc[m][n]*acc[m][n];
#pragma unroll
      for (int msk = 1; msk < 16; msk <<= 1){
#pragma unroll
        for (int j = 0; j < 4; j++) ss[j] += __shfl_xor(ss[j], msk);
      }
      f32x4 rr;
#pragma unroll
      for (int j = 0; j < 4; j++) rr[j] = rsqrtf(ss[j]*(1.0f/64.0f) + 1e-6f);
      float y[4][4];
#pragma unroll
      for (int n = 0; n < 4; n++)
#pragma unroll
        for (int j = 0; j < 4; j++) y[n][j] = acc[m][n][j]*rr[j]*g[n];
#pragma unroll
      for (int n = 0; n < 4; n++){
        const int d = n*16 + l15;
#pragma unroll
        for (int j = 0; j < 4; j++){
          const int s = row0 + m*16 + u*4 + j;
          float cs = cosp[s*64 + d], sn = sinp[s*64 + d];
          float part = (n < 2) ? -y[n+2][j] : y[n-2][j];
          ob[(size_t)s*ostr + ocol + d] = bf(y[n][j]*cs + part*sn);
        }
      }
    }
  } else {
    const int ocol = (unit-40)*64;
#pragma unroll
    for (int m = 0; m < 4; m++)
#pragma unroll
      for (int n = 0; n < 4; n++)
#pragma unroll
        for (int j = 0; j < 4; j++){
          const int s = row0 + m*16 + u*4 + j;
          vb[(size_t)s*512 + ocol + n*16 + l15] = bf(acc[m][n][j]);
        }
  }
}

// ---------------- generic GEMM (out-proj): C f32 = A[M][K] x B[N][K]^T ------
__global__ __launch_bounds__(256) void k_gemm_bt(const ushort* __restrict__ A,
                                                 const ushort* __restrict__ B,
                                                 float* __restrict__ C,
                                                 int M, int N, int K){
  __shared__ ushort As[128*64];
  __shared__ ushort Bs[128*64];
  const int tid = threadIdx.x, lane = tid & 63, wid = tid >> 6;
  const int bm = blockIdx.y * 128, bn = blockIdx.x * 128;
  const int wr = wid >> 1, wc = wid & 1;
  const int l15 = lane & 15, u = lane >> 4;

  const int srow = wid*32 + (lane >> 3);
  const int scol = ((lane & 7) ^ (lane >> 3)) * 8;
  const ushort* Abase = A + (size_t)(bm + srow) * K + scol;
  const ushort* Bbase = B + (size_t)(bn + srow) * K + scol;

  f32x4 acc[4][4] = {};

  for (int k0 = 0; k0 < K; k0 += 64){
    __syncthreads();
#pragma unroll
    for (int c = 0; c < 4; c++){
      gl_lds16(Abase + k0 + (size_t)c*8*K, As + (wid*32 + c*8)*64);
      gl_lds16(Bbase + k0 + (size_t)c*8*K, Bs + (wid*32 + c*8)*64);
    }
    __syncthreads();

#pragma unroll
    for (int kc = 0; kc < 2; kc++){
      bf16x8 af[4], bfr[4];
#pragma unroll
      for (int m = 0; m < 4; m++){
        int row = wr*64 + m*16 + l15;
        af[m] = *reinterpret_cast<const bf16x8*>(&As[row*64 + (((kc*4+u) ^ (row&7))*8)]);
      }
#pragma unroll
      for (int n = 0; n < 4; n++){
        int row = wc*64 + n*16 + l15;
        bfr[n] = *reinterpret_cast<const bf16x8*>(&Bs[row*64 + (((kc*4+u) ^ (row&7))*8)]);
      }
#pragma unroll
      for (int m = 0; m < 4; m++)
#pragma unroll
        for (int n = 0; n < 4; n++)
          acc[m][n] = __builtin_amdgcn_mfma_f32_16x16x32_bf16(af[m], bfr[n], acc[m][n], 0, 0, 0);
    }
  }

#pragma unroll
  for (int m = 0; m < 4; m++)
#pragma unroll
    for (int n = 0; n < 4; n++)
#pragma unroll
      for (int j = 0; j < 4; j++){
        int row = bm + wr*64 + m*16 + u*4 + j;
        int col = bn + wc*64 + n*16 + l15;
        C[(size_t)row * N + col] = acc[m][n][j];
      }
}

// ---------------- V transpose: vb bf16 [2048][512] -> vtb bf16 [512][2048] --
__global__ __launch_bounds__(256) void k_vtrans(const ushort* __restrict__ vb,
                                                ushort* __restrict__ vtb){
  __shared__ ushort tile[64][68];     // [d][s], pad 68
  const int vg = blockIdx.x >> 5, st = blockIdx.x & 31;
  const int tid = threadIdx.x;
#pragma unroll
  for (int i = 0; i < 4; i++){
    int idx = i*256 + tid;
    int r = idx >> 4, c4 = idx & 15;
    ushort4 v = *reinterpret_cast<const ushort4*>(
        vb + (size_t)(st*64 + r)*512 + vg*64 + c4*4);
    tile[c4*4+0][r] = v.x;
    tile[c4*4+1][r] = v.y;
    tile[c4*4+2][r] = v.z;
    tile[c4*4+3][r] = v.w;
  }
  __syncthreads();
#pragma unroll
  for (int i = 0; i < 4; i++){
    int idx = i*256 + tid;
    int d = idx >> 4, s4 = idx & 15;
    ushort4 o = *reinterpret_cast<const ushort4*>(&tile[d][s4*4]);
    *reinterpret_cast<ushort4*>(vtb + (size_t)(vg*64 + d)*SEQ + st*64 + s4*4) = o;
  }
}

// ---------------- causal flash GQA attention (swapped QK^T, O^T) ----------
// grid: 1024 blocks = 32 heads x 32 q-tiles of 64 rows, qt DESCENDING.
// 256 thr = 4 waves, 16 q-rows/wave. S^T = mfma(K,Q): q-row in-lane softmax.
// PV computes O^T = mfma(V^T-frag, P-frag): all softmax state stays in-lane.
__global__ __launch_bounds__(256) void k_attn(const ushort* __restrict__ qbuf,
                                              const ushort* __restrict__ kbuf,
                                              const ushort* __restrict__ vtb,
                                              ushort* __restrict__ ctx){
  __shared__ ushort Kd[2][64*64];       // swizzled K tiles   (16 KB)
  __shared__ ushort Vd[2][64*64];       // swizzled V^T tiles (16 KB)
  __shared__ ushort Plds[4][16*72];     // per-wave P [row][key] (9 KB)

  const int bx = blockIdx.x;
  const int h  = bx & 31;
  const int qt = 31 - (bx >> 5);        // descending: longest blocks first
  const int g = h >> 2;
  const int tid = threadIdx.x, lane = tid & 63, wid = tid >> 6;
  const int l15 = lane & 15, u = lane >> 4;
  const int q0 = qt*64 + wid*16;        // wave's first q-row
  const int tmax = qt;                  // last KV tile (inclusive)
  ushort* Pw = &Plds[wid][0];

  // Q fragments (B-operand: col=l15 -> q-row, k=(lane>>4)*8 within 32-chunk)
  bf16x8 qf[2];
#pragma unroll
  for (int kc = 0; kc < 2; kc++)
    qf[kc] = *reinterpret_cast<const bf16x8*>(
        qbuf + (size_t)(q0 + l15)*2048 + h*64 + kc*32 + u*8);

  f32x4 o[4] = {};                      // O^T: o[d0][j] = O[q=l15][d0*16+u*4+j]
  float mrun = -1e30f;                  // stats of q-row l15 (uniform across u)
  float lrun = 0.f;                     // PARTIAL per-lane sum (reduced at end)

  // staging: 8 chunks of 1KB per tile (8 rows x 128B); wave does 2 K + 2 V
  const int srow = wid*16 + (lane >> 3);
  const int scol = ((lane & 7) ^ (lane >> 3)) * 8;
  const ushort* ksrc0 = kbuf + (size_t)srow*512 + g*64 + scol;       // + t*64*512
  const ushort* vsrc0 = vtb  + (size_t)(g*64 + srow)*SEQ + scol;     // + t*64

  auto STAGE = [&](int buf, int t){
    const ushort* ks = ksrc0 + (size_t)t*64*512;
    gl_lds16(ks,         &Kd[buf][wid*1024]);
    gl_lds16(ks + 8*512, &Kd[buf][wid*1024 + 512]);
    const ushort* vs = vsrc0 + t*64;
    gl_lds16(vs,          &Vd[buf][wid*1024]);
    gl_lds16(vs + 8*SEQ,  &Vd[buf][wid*1024 + 512]);
  };

  STAGE(0, 0);
  __syncthreads();   // drains vmcnt(0): tile 0 visible

  for (int t = 0; t <= tmax; t++){
    const int cur = t & 1;
    if (t < tmax) STAGE(cur ^ 1, t + 1);

    const ushort* Kb = &Kd[cur][0];
    const ushort* Vb = &Vd[cur][0];
    const bool full = (t*64 + 63) <= q0;   // wave-uniform

    // ---- S^T = mfma(K, Q): lane holds key=kb*16+u*4+j for q-row l15 ----
    f32x4 st[4];
#pragma unroll
    for (int kb = 0; kb < 4; kb++){
      const int key0 = t*64 + kb*16;
      const int keyl = kb*16 + l15;
      if (key0 <= q0 + 15){
        bf16x8 kf0 = *reinterpret_cast<const bf16x8*>(&Kb[keyl*64 + ((u     ^ (keyl&7))*8)]);
        bf16x8 kf1 = *reinterpret_cast<const bf16x8*>(&Kb[keyl*64 + (((4|u) ^ (keyl&7))*8)]);
        f32x4 a = {};
        a = __builtin_amdgcn_mfma_f32_16x16x32_bf16(kf0, qf[0], a, 0, 0, 0);
        a = __builtin_amdgcn_mfma_f32_16x16x32_bf16(kf1, qf[1], a, 0, 0, 0);
        st[kb] = a;
      } else {
        st[kb] = (f32x4){-1e30f, -1e30f, -1e30f, -1e30f};
      }
    }
    if (!full){
      const int keyb = t*64 + u*4;
      const int qr = q0 + l15;
#pragma unroll
      for (int kb = 0; kb < 4; kb++)
#pragma unroll
        for (int j = 0; j < 4; j++)
          st[kb][j] = (keyb + kb*16 + j > qr) ? -1e30f : st[kb][j];
    }

    // ---- online softmax (defer-max; shfls only when a rescale fires) ----
    {
      f32x4 mx = st[0];
#pragma unroll
      for (int kb = 1; kb < 4; kb++)
#pragma unroll
        for (int j = 0; j < 4; j++) mx[j] = fmaxf(mx[j], st[kb][j]);
      float tml = fmaxf(fmaxf(mx[0], mx[1]), fmaxf(mx[2], mx[3]));
      if (__any(tml > mrun + THR2)){
        float tm = fmaxf(tml, __shfl_xor(tml, 16));
        tm = fmaxf(tm, __shfl_xor(tm, 32));
        float mn = fmaxf(mrun, tm);
        float al = exp2f(mrun - mn);
        mrun = mn;
        lrun *= al;
#pragma unroll
        for (int d0 = 0; d0 < 4; d0++)
#pragma unroll
          for (int j = 0; j < 4; j++) o[d0][j] *= al;   // in-lane: q-row = l15
      }

      // exp + partial row sum + packed P write (no cross-lane ops)
      float ls = 0.f;
#pragma unroll
      for (int kb = 0; kb < 4; kb++){
        ushort4 w;
#pragma unroll
        for (int j = 0; j < 4; j++){
          float p = exp2f(st[kb][j] - mrun);
          st[kb][j] = p;
          ls += p;
        }
        w.x = bf(st[kb][0]); w.y = bf(st[kb][1]);
        w.z = bf(st[kb][2]); w.w = bf(st[kb][3]);
        *reinterpret_cast<ushort4*>(&Pw[l15*72 + kb*16 + u*4]) = w;
      }
      lrun += ls;
    }

    // ---- O^T += V^T-frag x P-frag  (swapped operands -> q = out col) ----
    __builtin_amdgcn_s_setprio(1);
#pragma unroll
    for (int kc = 0; kc < 2; kc++){
      bf16x8 pa = *reinterpret_cast<const bf16x8*>(&Pw[l15*72 + kc*32 + u*8]);
#pragma unroll
      for (int d0 = 0; d0 < 4; d0++){
        const int vrow = d0*16 + l15;
        bf16x8 vb8 = *reinterpret_cast<const bf16x8*>(
            &Vb[vrow*64 + (((kc*4+u) ^ (vrow&7))*8)]);
        o[d0] = __builtin_amdgcn_mfma_f32_16x16x32_bf16(vb8, pa, o[d0], 0, 0, 0);
      }
    }
    __builtin_amdgcn_s_setprio(0);

    __syncthreads();  // publishes tile t+1 (vmcnt drain) + protects buffer reuse
  }

  // epilogue: reduce lrun across u-groups once; vectorized O^T store
  {
    float lt = lrun + __shfl_xor(lrun, 16);
    lt += __shfl_xor(lt, 32);
    float inv = 1.0f / lt;
#pragma unroll
    for (int d0 = 0; d0 < 4; d0++){
      ushort4 w;
      w.x = bf(o[d0][0] * inv); w.y = bf(o[d0][1] * inv);
      w.z = bf(o[d0][2] * inv); w.w = bf(o[d0][3] * inv);
      *reinterpret_cast<ushort4*>(
          &ctx[(size_t)(q0 + l15)*2048 + h*64 + d0*16 + u*4]) = w;
    }
  }
}

// ---------------- launcher ----------------
extern "C" void kernel_launch(void* const* d_in, const int* in_sizes, int n_in,
                              void* d_out, int out_size, void* d_ws, size_t ws_size,
                              hipStream_t stream){
  const float* x    = (const float*)d_in[0];
  // d_in[1] = mask (unused; causal mask computed analytically)
  const float* cosp = (const float*)d_in[2];
  const float* sinp = (const float*)d_in[3];
  const float* wq   = (const float*)d_in[4];
  const float* wk   = (const float*)d_in[5];
  const float* wv   = (const float*)d_in[6];
  const float* wo   = (const float*)d_in[7];
  const float* qg   = (const float*)d_in[8];
  const float* kg   = (const float*)d_in[9];
  float* out = (float*)d_out;

  char* ws = (char*)d_ws;
  ushort* xb   = (ushort*)(ws);                    //  8 MB  x bf16
  ushort* wcat = (ushort*)(ws + 8388608);          // 12 MB  [wq;wk;wv] bf16
  ushort* wob  = (ushort*)(ws + 20971520);         //  8 MB  wo bf16
  ushort* qb   = (ushort*)(ws + 29360128);         //  8 MB  q bf16 (pre-scaled)
  ushort* kb   = (ushort*)(ws + 37748736);         //  2 MB  k bf16 [2048][512]
  ushort* vb   = (ushort*)(ws + 39845888);         //  2 MB  v bf16 [2048][512]
  ushort* vtb  = (ushort*)(ws + 41943040);         //  2 MB  v^T bf16 [512][2048]
  ushort* ctxb = (ushort*)(ws + 44040192);         //  8 MB  ctx bf16
  // total 52,428,800 bytes

  k_cvt_all<<<14336, 256, 0, stream>>>(x, wq, wk, wv, wo, xb, wcat, wob);
  k_gemm_qkv<<<dim3(24, 16), 256, 0, stream>>>(xb, wcat, cosp, sinp, qg, kg,
                                               qb, kb, vb);
  k_vtrans<<<256, 256, 0, stream>>>(vb, vtb);
  k_attn<<<1024, 256, 0, stream>>>(qb, kb, vtb, ctxb);
  k_gemm_bt<<<dim3(16, 16), 256, 0, stream>>>(ctxb, wob, out, 2048, 2048, 2048);
}

// Round 6
// 150.943 us; speedup vs baseline: 1.1753x; 1.1753x over previous
//
#include <hip/hip_runtime.h>
#include <stdint.h>

// Problem constants (fixed-shape problem)
#define SEQ    2048
#define DMODEL 2048
#define NHEAD  32
#define NKV    8
#define HDIM   64
#define NQKV   3072   // 2048 q + 512 k + 512 v

typedef __bf16 bf16x8 __attribute__((ext_vector_type(8)));
typedef float  f32x4  __attribute__((ext_vector_type(4)));

#define SCALE2 0.180336880f   // 0.125 * log2(e): scores land in log2 domain
#define THR2   12.0f          // defer-max threshold (log2 domain); P <= 2^12

__device__ __forceinline__ ushort bf(float f){
  __bf16 h = (__bf16)f;               // native RNE convert on gfx950
  return __builtin_bit_cast(unsigned short, h);
}

__device__ __forceinline__ void gl_lds16(const void* g, void* l){
  __builtin_amdgcn_global_load_lds(
      (const __attribute__((address_space(1))) uint32_t*)g,
      (__attribute__((address_space(3))) uint32_t*)l, 16, 0, 0);
}

// ------------- all f32->bf16 converts in one kernel -------------
__global__ __launch_bounds__(256) void k_cvt_all(const float* __restrict__ x,
                                                 const float* __restrict__ wq,
                                                 const float* __restrict__ wk,
                                                 const float* __restrict__ wv,
                                                 const float* __restrict__ wo,
                                                 ushort* __restrict__ xb,
                                                 ushort* __restrict__ wcat,
                                                 ushort* __restrict__ wob){
  int i = blockIdx.x * 256 + threadIdx.x;
  const float* src; ushort* dst; int s4; int d4;
  if (i < 1048576)      { src = x;  dst = xb;   s4 = i;           d4 = s4; }
  else if (i < 2097152) { src = wq; dst = wcat; s4 = i - 1048576; d4 = s4; }
  else if (i < 2359296) { src = wk; dst = wcat; s4 = i - 2097152; d4 = s4 + 1048576; }
  else if (i < 2621440) { src = wv; dst = wcat; s4 = i - 2359296; d4 = s4 + 1310720; }
  else                  { src = wo; dst = wob;  s4 = i - 2621440; d4 = s4; }
  float4 v = reinterpret_cast<const float4*>(src)[s4];
  ushort4 o;
  o.x = bf(v.x); o.y = bf(v.y); o.z = bf(v.z); o.w = bf(v.w);
  reinterpret_cast<ushort4*>(dst)[d4] = o;
}

// ---------------- GEMM: C[m][n] = sum_k A[m][k] * B[n][k] ----------------
// 128x128 tile, BK=64, 4 waves (2x2). 2-PHASE pipeline (T3 minimum):
// STAGE(t+1) issued before compute(t); ONE barrier per K-step (drains vmcnt).
// Double-buffered LDS (64 KB). XOR-swizzled source + matching ds_read.
__global__ __launch_bounds__(256) void k_gemm_bt(const ushort* __restrict__ A,
                                                 const ushort* __restrict__ B,
                                                 float* __restrict__ C,
                                                 int M, int N, int K){
  __shared__ ushort As[2][128*64];
  __shared__ ushort Bs[2][128*64];
  const int tid = threadIdx.x, lane = tid & 63, wid = tid >> 6;
  const int bm = blockIdx.y * 128, bn = blockIdx.x * 128;
  const int wr = wid >> 1, wc = wid & 1;
  const int l15 = lane & 15, u = lane >> 4;

  // staging: wave covers 32 rows (4 chunks of 8 rows x 128B)
  const int srow = wid*32 + (lane >> 3);
  const int scol = ((lane & 7) ^ (lane >> 3)) * 8;   // pre-swizzled k-chunk
  const ushort* Abase = A + (size_t)(bm + srow) * K + scol;
  const ushort* Bbase = B + (size_t)(bn + srow) * K + scol;

  auto STAGE = [&](int buf, int k0){
#pragma unroll
    for (int c = 0; c < 4; c++){
      gl_lds16(Abase + k0 + (size_t)c*8*K, &As[buf][(wid*32 + c*8)*64]);
      gl_lds16(Bbase + k0 + (size_t)c*8*K, &Bs[buf][(wid*32 + c*8)*64]);
    }
  };

  f32x4 acc[4][4] = {};
  const int NT = K >> 6;

  STAGE(0, 0);
  __syncthreads();                       // drain vmcnt(0): tile 0 visible

  for (int t = 0; t < NT; t++){
    const int cur = t & 1;
    if (t + 1 < NT) STAGE(cur ^ 1, (t + 1) << 6);   // loads fly under compute

#pragma unroll
    for (int kc = 0; kc < 2; kc++){
      bf16x8 af[4], bfr[4];
#pragma unroll
      for (int m = 0; m < 4; m++){
        int row = wr*64 + m*16 + l15;
        af[m] = *reinterpret_cast<const bf16x8*>(&As[cur][row*64 + (((kc*4+u) ^ (row&7))*8)]);
      }
#pragma unroll
      for (int n = 0; n < 4; n++){
        int row = wc*64 + n*16 + l15;
        bfr[n] = *reinterpret_cast<const bf16x8*>(&Bs[cur][row*64 + (((kc*4+u) ^ (row&7))*8)]);
      }
      __builtin_amdgcn_s_setprio(1);
#pragma unroll
      for (int m = 0; m < 4; m++)
#pragma unroll
        for (int n = 0; n < 4; n++)
          acc[m][n] = __builtin_amdgcn_mfma_f32_16x16x32_bf16(af[m], bfr[n], acc[m][n], 0, 0, 0);
      __builtin_amdgcn_s_setprio(0);
    }

    __syncthreads();   // drains vmcnt(0): publishes t+1, protects reused buffer
  }

  // epilogue: C/D layout col=lane&15, row=(lane>>4)*4+j
#pragma unroll
  for (int m = 0; m < 4; m++)
#pragma unroll
    for (int n = 0; n < 4; n++)
#pragma unroll
      for (int j = 0; j < 4; j++){
        int row = bm + wr*64 + m*16 + u*4 + j;
        int col = bn + wc*64 + n*16 + l15;
        C[(size_t)row * N + col] = acc[m][n][j];
      }
}

// ---------------- fused RMSNorm + RoPE + bf16 cast (q, k only) ----------------
// qkv: [SEQ][3072] f32.  Outputs: qb [SEQ][2048] (pre-scaled by SCALE2),
// kb [SEQ][512] bf16.
__global__ __launch_bounds__(256) void k_normrope(const float* __restrict__ qkv,
                                                  const float* __restrict__ cosp,
                                                  const float* __restrict__ sinp,
                                                  const float* __restrict__ qg,
                                                  const float* __restrict__ kg,
                                                  ushort* __restrict__ qb,
                                                  ushort* __restrict__ kb){
  const int s = blockIdx.x;
  const int tid = threadIdx.x, lane = tid & 63, wid = tid >> 6;
  const float* row = qkv + (size_t)s * NQKV;
  const float cs = cosp[s*HDIM + lane];
  const float sn = sinp[s*HDIM + lane];

  for (int hidx = wid; hidx < 40; hidx += 4){
    const bool isq = hidx < 32;
    const int col = isq ? hidx*64 : 2048 + (hidx-32)*64;
    float x = row[col + lane];
    float ss = x * x;
#pragma unroll
    for (int m = 1; m < 64; m <<= 1) ss += __shfl_xor(ss, m);
    float r = rsqrtf(ss * (1.0f/64.0f) + 1e-6f);
    float y = x * r * (isq ? qg : kg)[lane];
    // HF RoPE: out[d] = y[d]*cos[d] + (d<32 ? -y[d+32] : y[d-32])*sin[d]
    float p = __shfl_xor(y, 32);
    float out = y * cs + (lane < 32 ? -p : p) * sn;
    if (isq) qb[(size_t)s*2048 + hidx*64 + lane] = bf(out * SCALE2);
    else     kb[(size_t)s*512 + (hidx-32)*64 + lane] = bf(out);
  }
}

// ---------------- V transpose: qkvf v-section (f32) -> vtb bf16 [g][d][s] ----
__global__ __launch_bounds__(256) void k_vtrans(const float* __restrict__ qkvf,
                                                ushort* __restrict__ vtb){
  __shared__ ushort tile[64][68];     // [d][s], pad 68
  const int g = blockIdx.x >> 5, st = blockIdx.x & 31;
  const int tid = threadIdx.x;
#pragma unroll
  for (int i = 0; i < 4; i++){
    int idx = i*256 + tid;
    int r = idx >> 4, c4 = idx & 15;       // r: s-row 0..63, c4: 4-d group
    float4 v = *reinterpret_cast<const float4*>(
        qkvf + (size_t)(st*64 + r)*NQKV + 2560 + g*64 + c4*4);
    tile[c4*4+0][r] = bf(v.x);
    tile[c4*4+1][r] = bf(v.y);
    tile[c4*4+2][r] = bf(v.z);
    tile[c4*4+3][r] = bf(v.w);
  }
  __syncthreads();
#pragma unroll
  for (int i = 0; i < 4; i++){
    int idx = i*256 + tid;
    int d = idx >> 4, s4 = idx & 15;
    ushort4 o = *reinterpret_cast<const ushort4*>(&tile[d][s4*4]);
    *reinterpret_cast<ushort4*>(vtb + (size_t)(g*64 + d)*SEQ + st*64 + s4*4) = o;
  }
}

// ---------------- causal flash GQA attention (swapped QK^T, O^T) ----------
// grid: 1024 blocks = 32 heads x 32 q-tiles of 64 rows, qt DESCENDING.
// 256 thr = 4 waves, 16 q-rows/wave. S^T = mfma(K,Q): q-row in-lane softmax.
// PV computes O^T = mfma(V^T-frag, P-frag): all softmax state stays in-lane.
__global__ __launch_bounds__(256) void k_attn(const ushort* __restrict__ qbuf,
                                              const ushort* __restrict__ kbuf,
                                              const ushort* __restrict__ vtb,
                                              ushort* __restrict__ ctx){
  __shared__ ushort Kd[2][64*64];       // swizzled K tiles   (16 KB)
  __shared__ ushort Vd[2][64*64];       // swizzled V^T tiles (16 KB)
  __shared__ ushort Plds[4][16*72];     // per-wave P [row][key] (9 KB)

  const int bx = blockIdx.x;
  const int h  = bx & 31;
  const int qt = 31 - (bx >> 5);        // descending: longest blocks first
  const int g = h >> 2;
  const int tid = threadIdx.x, lane = tid & 63, wid = tid >> 6;
  const int l15 = lane & 15, u = lane >> 4;
  const int q0 = qt*64 + wid*16;        // wave's first q-row
  const int tmax = qt;                  // last KV tile (inclusive)
  ushort* Pw = &Plds[wid][0];

  // Q fragments (B-operand: col=l15 -> q-row, k=(lane>>4)*8 within 32-chunk)
  bf16x8 qf[2];
#pragma unroll
  for (int kc = 0; kc < 2; kc++)
    qf[kc] = *reinterpret_cast<const bf16x8*>(
        qbuf + (size_t)(q0 + l15)*2048 + h*64 + kc*32 + u*8);

  f32x4 o[4] = {};                      // O^T: o[d0][j] = O[q=l15][d0*16+u*4+j]
  float mrun = -1e30f;                  // stats of q-row l15 (uniform across u)
  float lrun = 0.f;                     // PARTIAL per-lane sum (reduced at end)

  // staging: 8 chunks of 1KB per tile (8 rows x 128B); wave does 2 K + 2 V
  const int srow = wid*16 + (lane >> 3);
  const int scol = ((lane & 7) ^ (lane >> 3)) * 8;
  const ushort* ksrc0 = kbuf + (size_t)srow*512 + g*64 + scol;       // + t*64*512
  const ushort* vsrc0 = vtb  + (size_t)(g*64 + srow)*SEQ + scol;     // + t*64

  auto STAGE = [&](int buf, int t){
    const ushort* ks = ksrc0 + (size_t)t*64*512;
    gl_lds16(ks,         &Kd[buf][wid*1024]);
    gl_lds16(ks + 8*512, &Kd[buf][wid*1024 + 512]);
    const ushort* vs = vsrc0 + t*64;
    gl_lds16(vs,          &Vd[buf][wid*1024]);
    gl_lds16(vs + 8*SEQ,  &Vd[buf][wid*1024 + 512]);
  };

  STAGE(0, 0);
  __syncthreads();   // drains vmcnt(0): tile 0 visible

  for (int t = 0; t <= tmax; t++){
    const int cur = t & 1;
    if (t < tmax) STAGE(cur ^ 1, t + 1);

    const ushort* Kb = &Kd[cur][0];
    const ushort* Vb = &Vd[cur][0];
    const bool full = (t*64 + 63) <= q0;   // wave-uniform

    // ---- S^T = mfma(K, Q): lane holds key=kb*16+u*4+j for q-row l15 ----
    f32x4 st[4];
#pragma unroll
    for (int kb = 0; kb < 4; kb++){
      const int key0 = t*64 + kb*16;
      const int keyl = kb*16 + l15;
      if (key0 <= q0 + 15){
        bf16x8 kf0 = *reinterpret_cast<const bf16x8*>(&Kb[keyl*64 + ((u     ^ (keyl&7))*8)]);
        bf16x8 kf1 = *reinterpret_cast<const bf16x8*>(&Kb[keyl*64 + (((4|u) ^ (keyl&7))*8)]);
        f32x4 a = {};
        a = __builtin_amdgcn_mfma_f32_16x16x32_bf16(kf0, qf[0], a, 0, 0, 0);
        a = __builtin_amdgcn_mfma_f32_16x16x32_bf16(kf1, qf[1], a, 0, 0, 0);
        st[kb] = a;
      } else {
        st[kb] = (f32x4){-1e30f, -1e30f, -1e30f, -1e30f};
      }
    }
    if (!full){
      const int keyb = t*64 + u*4;
      const int qr = q0 + l15;
#pragma unroll
      for (int kb = 0; kb < 4; kb++)
#pragma unroll
        for (int j = 0; j < 4; j++)
          st[kb][j] = (keyb + kb*16 + j > qr) ? -1e30f : st[kb][j];
    }

    // ---- online softmax (defer-max; shfls only when a rescale fires) ----
    {
      f32x4 mx = st[0];
#pragma unroll
      for (int kb = 1; kb < 4; kb++)
#pragma unroll
        for (int j = 0; j < 4; j++) mx[j] = fmaxf(mx[j], st[kb][j]);
      float tml = fmaxf(fmaxf(mx[0], mx[1]), fmaxf(mx[2], mx[3]));
      if (__any(tml > mrun + THR2)){
        float tm = fmaxf(tml, __shfl_xor(tml, 16));
        tm = fmaxf(tm, __shfl_xor(tm, 32));
        float mn = fmaxf(mrun, tm);
        float al = exp2f(mrun - mn);
        mrun = mn;
        lrun *= al;
#pragma unroll
        for (int d0 = 0; d0 < 4; d0++)
#pragma unroll
          for (int j = 0; j < 4; j++) o[d0][j] *= al;   // in-lane: q-row = l15
      }

      // exp + partial row sum + packed P write (no cross-lane ops)
      float ls = 0.f;
#pragma unroll
      for (int kb = 0; kb < 4; kb++){
        ushort4 w;
#pragma unroll
        for (int j = 0; j < 4; j++){
          float p = exp2f(st[kb][j] - mrun);
          st[kb][j] = p;
          ls += p;
        }
        w.x = bf(st[kb][0]); w.y = bf(st[kb][1]);
        w.z = bf(st[kb][2]); w.w = bf(st[kb][3]);
        *reinterpret_cast<ushort4*>(&Pw[l15*72 + kb*16 + u*4]) = w;
      }
      lrun += ls;
    }

    // ---- O^T += V^T-frag x P-frag  (swapped operands -> q = out col) ----
    __builtin_amdgcn_s_setprio(1);
#pragma unroll
    for (int kc = 0; kc < 2; kc++){
      bf16x8 pa = *reinterpret_cast<const bf16x8*>(&Pw[l15*72 + kc*32 + u*8]);
#pragma unroll
      for (int d0 = 0; d0 < 4; d0++){
        const int vrow = d0*16 + l15;
        bf16x8 vb8 = *reinterpret_cast<const bf16x8*>(
            &Vb[vrow*64 + (((kc*4+u) ^ (vrow&7))*8)]);
        o[d0] = __builtin_amdgcn_mfma_f32_16x16x32_bf16(vb8, pa, o[d0], 0, 0, 0);
      }
    }
    __builtin_amdgcn_s_setprio(0);

    __syncthreads();  // publishes tile t+1 (vmcnt drain) + protects buffer reuse
  }

  // epilogue: reduce lrun across u-groups once; vectorized O^T store
  {
    float lt = lrun + __shfl_xor(lrun, 16);
    lt += __shfl_xor(lt, 32);
    float inv = 1.0f / lt;
#pragma unroll
    for (int d0 = 0; d0 < 4; d0++){
      ushort4 w;
      w.x = bf(o[d0][0] * inv); w.y = bf(o[d0][1] * inv);
      w.z = bf(o[d0][2] * inv); w.w = bf(o[d0][3] * inv);
      *reinterpret_cast<ushort4*>(
          &ctx[(size_t)(q0 + l15)*2048 + h*64 + d0*16 + u*4]) = w;
    }
  }
}

// ---------------- launcher ----------------
extern "C" void kernel_launch(void* const* d_in, const int* in_sizes, int n_in,
                              void* d_out, int out_size, void* d_ws, size_t ws_size,
                              hipStream_t stream){
  const float* x    = (const float*)d_in[0];
  // d_in[1] = mask (unused; causal mask computed analytically)
  const float* cosp = (const float*)d_in[2];
  const float* sinp = (const float*)d_in[3];
  const float* wq   = (const float*)d_in[4];
  const float* wk   = (const float*)d_in[5];
  const float* wv   = (const float*)d_in[6];
  const float* wo   = (const float*)d_in[7];
  const float* qg   = (const float*)d_in[8];
  const float* kg   = (const float*)d_in[9];
  float* out = (float*)d_out;

  char* ws = (char*)d_ws;
  ushort* xb   = (ushort*)(ws);                    //  8 MB  x bf16
  ushort* wcat = (ushort*)(ws + 8388608);          // 12 MB  [wq;wk;wv] bf16
  ushort* wob  = (ushort*)(ws + 20971520);         //  8 MB  wo bf16
  float*  qkvf = (float* )(ws + 29360128);         // 24 MB  qkv f32 [2048][3072]
  ushort* qb   = (ushort*)(ws + 54525952);         //  8 MB  q bf16 (pre-scaled)
  ushort* kb   = (ushort*)(ws + 62914560);         //  2 MB  k bf16 [2048][512]
  ushort* vtb  = (ushort*)(ws + 65011712);         //  2 MB  v^T bf16 [512][2048]
  ushort* ctxb = (ushort*)(ws + 67108864);         //  8 MB  ctx bf16
  // total 75,497,472 bytes

  k_cvt_all<<<14336, 256, 0, stream>>>(x, wq, wk, wv, wo, xb, wcat, wob);
  k_gemm_bt<<<dim3(24, 16), 256, 0, stream>>>(xb, wcat, qkvf, 2048, 3072, 2048);
  k_normrope<<<2048, 256, 0, stream>>>(qkvf, cosp, sinp, qg, kg, qb, kb);
  k_vtrans<<<256, 256, 0, stream>>>(qkvf, vtb);
  k_attn<<<1024, 256, 0, stream>>>(qb, kb, vtb, ctxb);
  k_gemm_bt<<<dim3(16, 16), 256, 0, stream>>>(ctxb, wob, out, 2048, 2048, 2048);
}

// Round 7
// 150.491 us; speedup vs baseline: 1.1789x; 1.0030x over previous
//
#include <hip/hip_runtime.h>
#include <stdint.h>

// Problem constants (fixed-shape problem)
#define SEQ    2048
#define DMODEL 2048
#define NHEAD  32
#define NKV    8
#define HDIM   64
#define NQKV   3072   // 2048 q + 512 k + 512 v

typedef __bf16 bf16x8 __attribute__((ext_vector_type(8)));
typedef float  f32x4  __attribute__((ext_vector_type(4)));

#define SCALE2 0.180336880f   // 0.125 * log2(e): scores land in log2 domain
#define THR2   12.0f          // defer-max threshold (log2 domain); P <= 2^12

__device__ __forceinline__ ushort bf(float f){
  __bf16 h = (__bf16)f;               // native RNE convert on gfx950
  return __builtin_bit_cast(unsigned short, h);
}

__device__ __forceinline__ void gl_lds16(const void* g, void* l){
  __builtin_amdgcn_global_load_lds(
      (const __attribute__((address_space(1))) uint32_t*)g,
      (__attribute__((address_space(3))) uint32_t*)l, 16, 0, 0);
}

// ------------- all f32->bf16 converts in one kernel -------------
__global__ __launch_bounds__(256) void k_cvt_all(const float* __restrict__ x,
                                                 const float* __restrict__ wq,
                                                 const float* __restrict__ wk,
                                                 const float* __restrict__ wv,
                                                 const float* __restrict__ wo,
                                                 ushort* __restrict__ xb,
                                                 ushort* __restrict__ wcat,
                                                 ushort* __restrict__ wob){
  int i = blockIdx.x * 256 + threadIdx.x;
  const float* src; ushort* dst; int s4; int d4;
  if (i < 1048576)      { src = x;  dst = xb;   s4 = i;           d4 = s4; }
  else if (i < 2097152) { src = wq; dst = wcat; s4 = i - 1048576; d4 = s4; }
  else if (i < 2359296) { src = wk; dst = wcat; s4 = i - 2097152; d4 = s4 + 1048576; }
  else if (i < 2621440) { src = wv; dst = wcat; s4 = i - 2359296; d4 = s4 + 1310720; }
  else                  { src = wo; dst = wob;  s4 = i - 2621440; d4 = s4; }
  float4 v = reinterpret_cast<const float4*>(src)[s4];
  ushort4 o;
  o.x = bf(v.x); o.y = bf(v.y); o.z = bf(v.z); o.w = bf(v.w);
  reinterpret_cast<ushort4*>(dst)[d4] = o;
}

// ---------------- GEMM: C[m][n] = sum_k A[m][k] * B[n][k] ----------------
// 128x128 tile, BK=64, 4 waves (2x2). 2-PHASE pipeline: STAGE(t+1) issued
// before compute(t); ONE barrier per K-step (drains vmcnt). Double-buffered.
__global__ __launch_bounds__(256) void k_gemm_bt(const ushort* __restrict__ A,
                                                 const ushort* __restrict__ B,
                                                 float* __restrict__ C,
                                                 int M, int N, int K){
  __shared__ ushort As[2][128*64];
  __shared__ ushort Bs[2][128*64];
  const int tid = threadIdx.x, lane = tid & 63, wid = tid >> 6;
  const int bm = blockIdx.y * 128, bn = blockIdx.x * 128;
  const int wr = wid >> 1, wc = wid & 1;
  const int l15 = lane & 15, u = lane >> 4;

  // staging: wave covers 32 rows (4 chunks of 8 rows x 128B)
  const int srow = wid*32 + (lane >> 3);
  const int scol = ((lane & 7) ^ (lane >> 3)) * 8;   // pre-swizzled k-chunk
  const ushort* Abase = A + (size_t)(bm + srow) * K + scol;
  const ushort* Bbase = B + (size_t)(bn + srow) * K + scol;

  auto STAGE = [&](int buf, int k0){
#pragma unroll
    for (int c = 0; c < 4; c++){
      gl_lds16(Abase + k0 + (size_t)c*8*K, &As[buf][(wid*32 + c*8)*64]);
      gl_lds16(Bbase + k0 + (size_t)c*8*K, &Bs[buf][(wid*32 + c*8)*64]);
    }
  };

  f32x4 acc[4][4] = {};
  const int NT = K >> 6;

  STAGE(0, 0);
  __syncthreads();                       // drain vmcnt(0): tile 0 visible

  for (int t = 0; t < NT; t++){
    const int cur = t & 1;
    if (t + 1 < NT) STAGE(cur ^ 1, (t + 1) << 6);   // loads fly under compute

#pragma unroll
    for (int kc = 0; kc < 2; kc++){
      bf16x8 af[4], bfr[4];
#pragma unroll
      for (int m = 0; m < 4; m++){
        int row = wr*64 + m*16 + l15;
        af[m] = *reinterpret_cast<const bf16x8*>(&As[cur][row*64 + (((kc*4+u) ^ (row&7))*8)]);
      }
#pragma unroll
      for (int n = 0; n < 4; n++){
        int row = wc*64 + n*16 + l15;
        bfr[n] = *reinterpret_cast<const bf16x8*>(&Bs[cur][row*64 + (((kc*4+u) ^ (row&7))*8)]);
      }
      __builtin_amdgcn_s_setprio(1);
#pragma unroll
      for (int m = 0; m < 4; m++)
#pragma unroll
        for (int n = 0; n < 4; n++)
          acc[m][n] = __builtin_amdgcn_mfma_f32_16x16x32_bf16(af[m], bfr[n], acc[m][n], 0, 0, 0);
      __builtin_amdgcn_s_setprio(0);
    }

    __syncthreads();   // drains vmcnt(0): publishes t+1, protects reused buffer
  }

  // epilogue: C/D layout col=lane&15, row=(lane>>4)*4+j
#pragma unroll
  for (int m = 0; m < 4; m++)
#pragma unroll
    for (int n = 0; n < 4; n++)
#pragma unroll
      for (int j = 0; j < 4; j++){
        int row = bm + wr*64 + m*16 + u*4 + j;
        int col = bn + wc*64 + n*16 + l15;
        C[(size_t)row * N + col] = acc[m][n][j];
      }
}

// ---------------- fused RMSNorm + RoPE + bf16 cast (q, k only) ----------------
__global__ __launch_bounds__(256) void k_normrope(const float* __restrict__ qkv,
                                                  const float* __restrict__ cosp,
                                                  const float* __restrict__ sinp,
                                                  const float* __restrict__ qg,
                                                  const float* __restrict__ kg,
                                                  ushort* __restrict__ qb,
                                                  ushort* __restrict__ kb){
  const int s = blockIdx.x;
  const int tid = threadIdx.x, lane = tid & 63, wid = tid >> 6;
  const float* row = qkv + (size_t)s * NQKV;
  const float cs = cosp[s*HDIM + lane];
  const float sn = sinp[s*HDIM + lane];

  for (int hidx = wid; hidx < 40; hidx += 4){
    const bool isq = hidx < 32;
    const int col = isq ? hidx*64 : 2048 + (hidx-32)*64;
    float x = row[col + lane];
    float ss = x * x;
#pragma unroll
    for (int m = 1; m < 64; m <<= 1) ss += __shfl_xor(ss, m);
    float r = rsqrtf(ss * (1.0f/64.0f) + 1e-6f);
    float y = x * r * (isq ? qg : kg)[lane];
    // HF RoPE: out[d] = y[d]*cos[d] + (d<32 ? -y[d+32] : y[d-32])*sin[d]
    float p = __shfl_xor(y, 32);
    float out = y * cs + (lane < 32 ? -p : p) * sn;
    if (isq) qb[(size_t)s*2048 + hidx*64 + lane] = bf(out * SCALE2);
    else     kb[(size_t)s*512 + (hidx-32)*64 + lane] = bf(out);
  }
}

// ---------------- V transpose: qkvf v-section (f32) -> vtb bf16 ----------------
// vtb rows = g*64+d; within each 64-key tile, keys stored in PV-slot order:
// 4-key chunk (kb,u) -> position (kb>>1)*32 + u*8 + (kb&1)*4.  This makes the
// attention PV B-operand (P) a pure in-lane repack (no LDS roundtrip).
__global__ __launch_bounds__(256) void k_vtrans(const float* __restrict__ qkvf,
                                                ushort* __restrict__ vtb){
  __shared__ ushort tile[64][68];     // [d][s], pad 68
  const int g = blockIdx.x >> 5, st = blockIdx.x & 31;
  const int tid = threadIdx.x;
#pragma unroll
  for (int i = 0; i < 4; i++){
    int idx = i*256 + tid;
    int r = idx >> 4, c4 = idx & 15;       // r: s-row 0..63, c4: 4-d group
    float4 v = *reinterpret_cast<const float4*>(
        qkvf + (size_t)(st*64 + r)*NQKV + 2560 + g*64 + c4*4);
    tile[c4*4+0][r] = bf(v.x);
    tile[c4*4+1][r] = bf(v.y);
    tile[c4*4+2][r] = bf(v.z);
    tile[c4*4+3][r] = bf(v.w);
  }
  __syncthreads();
#pragma unroll
  for (int i = 0; i < 4; i++){
    int idx = i*256 + tid;
    int d = idx >> 4, s4 = idx & 15;
    // sigma: key chunk s4=(kb,u) -> slot-ordered position
    int pos4 = (s4 >> 3)*32 + (s4 & 3)*8 + ((s4 >> 2) & 1)*4;
    ushort4 o = *reinterpret_cast<const ushort4*>(&tile[d][s4*4]);
    *reinterpret_cast<ushort4*>(vtb + (size_t)(g*64 + d)*SEQ + st*64 + pos4) = o;
  }
}

// ---------------- causal flash GQA attention (swapped QK^T, O^T) ----------
// grid: 1024 blocks = 32 heads x 32 q-tiles of 64 rows, qt DESCENDING.
// 256 thr = 4 waves, 16 q-rows/wave. S^T = mfma(K,Q): q-row in-lane softmax.
// PV: O^T = mfma(V^T-frag, P-frag) with P packed IN-LANE (k-dim permuted
// consistently in vtb) -> no P LDS roundtrip, LDS = K/V dbuf only (32 KB).
__global__ __launch_bounds__(256) void k_attn(const ushort* __restrict__ qbuf,
                                              const ushort* __restrict__ kbuf,
                                              const ushort* __restrict__ vtb,
                                              ushort* __restrict__ ctx){
  __shared__ ushort Kd[2][64*64];       // swizzled K tiles   (16 KB)
  __shared__ ushort Vd[2][64*64];       // swizzled V^T tiles (16 KB)

  const int bx = blockIdx.x;
  const int h  = bx & 31;
  const int qt = 31 - (bx >> 5);        // descending: longest blocks first
  const int g = h >> 2;
  const int tid = threadIdx.x, lane = tid & 63, wid = tid >> 6;
  const int l15 = lane & 15, u = lane >> 4;
  const int q0 = qt*64 + wid*16;        // wave's first q-row
  const int tmax = qt;                  // last KV tile (inclusive)

  // Q fragments (B-operand: col=l15 -> q-row, k=(lane>>4)*8 within 32-chunk)
  bf16x8 qf[2];
#pragma unroll
  for (int kc = 0; kc < 2; kc++)
    qf[kc] = *reinterpret_cast<const bf16x8*>(
        qbuf + (size_t)(q0 + l15)*2048 + h*64 + kc*32 + u*8);

  f32x4 o[4] = {};                      // O^T: o[d0][j] = O[q=l15][d0*16+u*4+j]
  float mrun = -1e30f;                  // stats of q-row l15 (uniform across u)
  float lrun = 0.f;                     // PARTIAL per-lane sum (reduced at end)

  // staging: 8 chunks of 1KB per tile (8 rows x 128B); wave does 2 K + 2 V
  const int srow = wid*16 + (lane >> 3);
  const int scol = ((lane & 7) ^ (lane >> 3)) * 8;
  const ushort* ksrc0 = kbuf + (size_t)srow*512 + g*64 + scol;       // + t*64*512
  const ushort* vsrc0 = vtb  + (size_t)(g*64 + srow)*SEQ + scol;     // + t*64

  auto STAGE = [&](int buf, int t){
    const ushort* ks = ksrc0 + (size_t)t*64*512;
    gl_lds16(ks,         &Kd[buf][wid*1024]);
    gl_lds16(ks + 8*512, &Kd[buf][wid*1024 + 512]);
    const ushort* vs = vsrc0 + t*64;
    gl_lds16(vs,          &Vd[buf][wid*1024]);
    gl_lds16(vs + 8*SEQ,  &Vd[buf][wid*1024 + 512]);
  };

  STAGE(0, 0);
  __syncthreads();   // drains vmcnt(0): tile 0 visible

  for (int t = 0; t <= tmax; t++){
    const int cur = t & 1;
    if (t < tmax) STAGE(cur ^ 1, t + 1);

    const ushort* Kb = &Kd[cur][0];
    const ushort* Vb = &Vd[cur][0];
    const bool full = (t*64 + 63) <= q0;   // wave-uniform

    // ---- S^T = mfma(K, Q): lane holds key=kb*16+u*4+j for q-row l15 ----
    f32x4 st[4];
#pragma unroll
    for (int kb = 0; kb < 4; kb++){
      const int key0 = t*64 + kb*16;
      const int keyl = kb*16 + l15;
      if (key0 <= q0 + 15){
        bf16x8 kf0 = *reinterpret_cast<const bf16x8*>(&Kb[keyl*64 + ((u     ^ (keyl&7))*8)]);
        bf16x8 kf1 = *reinterpret_cast<const bf16x8*>(&Kb[keyl*64 + (((4|u) ^ (keyl&7))*8)]);
        f32x4 a = {};
        a = __builtin_amdgcn_mfma_f32_16x16x32_bf16(kf0, qf[0], a, 0, 0, 0);
        a = __builtin_amdgcn_mfma_f32_16x16x32_bf16(kf1, qf[1], a, 0, 0, 0);
        st[kb] = a;
      } else {
        st[kb] = (f32x4){-1e30f, -1e30f, -1e30f, -1e30f};
      }
    }
    if (!full){
      const int keyb = t*64 + u*4;
      const int qr = q0 + l15;
#pragma unroll
      for (int kb = 0; kb < 4; kb++)
#pragma unroll
        for (int j = 0; j < 4; j++)
          st[kb][j] = (keyb + kb*16 + j > qr) ? -1e30f : st[kb][j];
    }

    // ---- online softmax (defer-max; shfls only when a rescale fires) ----
    {
      f32x4 mx = st[0];
#pragma unroll
      for (int kb = 1; kb < 4; kb++)
#pragma unroll
        for (int j = 0; j < 4; j++) mx[j] = fmaxf(mx[j], st[kb][j]);
      float tml = fmaxf(fmaxf(mx[0], mx[1]), fmaxf(mx[2], mx[3]));
      if (__any(tml > mrun + THR2)){
        float tm = fmaxf(tml, __shfl_xor(tml, 16));
        tm = fmaxf(tm, __shfl_xor(tm, 32));
        float mn = fmaxf(mrun, tm);
        float al = exp2f(mrun - mn);
        mrun = mn;
        lrun *= al;
#pragma unroll
        for (int d0 = 0; d0 < 4; d0++)
#pragma unroll
          for (int j = 0; j < 4; j++) o[d0][j] *= al;   // in-lane: q-row = l15
      }

      // exp + partial row sum (no cross-lane ops, no LDS)
#pragma unroll
      for (int kb = 0; kb < 4; kb++)
#pragma unroll
        for (int j = 0; j < 4; j++){
          float p = exp2f(st[kb][j] - mrun);
          st[kb][j] = p;
          lrun += p;
        }
    }

    // ---- O^T += V^T-frag x P-frag; P packed IN-LANE (k-dim permuted) ----
    // slot(kc,u,e) <-> key (2kc+(e>>2))*16 + u*4 + (e&3); vtb pre-permuted.
    __builtin_amdgcn_s_setprio(1);
#pragma unroll
    for (int kc = 0; kc < 2; kc++){
      bf16x8 pb;
#pragma unroll
      for (int e = 0; e < 4; e++){
        pb[e]   = (__bf16)st[2*kc  ][e];
        pb[4+e] = (__bf16)st[2*kc+1][e];
      }
#pragma unroll
      for (int d0 = 0; d0 < 4; d0++){
        const int vrow = d0*16 + l15;
        bf16x8 vb8 = *reinterpret_cast<const bf16x8*>(
            &Vb[vrow*64 + (((kc*4+u) ^ (vrow&7))*8)]);
        o[d0] = __builtin_amdgcn_mfma_f32_16x16x32_bf16(vb8, pb, o[d0], 0, 0, 0);
      }
    }
    __builtin_amdgcn_s_setprio(0);

    __syncthreads();  // publishes tile t+1 (vmcnt drain) + protects buffer reuse
  }

  // epilogue: reduce lrun across u-groups once; vectorized O^T store
  {
    float lt = lrun + __shfl_xor(lrun, 16);
    lt += __shfl_xor(lt, 32);
    float inv = 1.0f / lt;
#pragma unroll
    for (int d0 = 0; d0 < 4; d0++){
      ushort4 w;
      w.x = bf(o[d0][0] * inv); w.y = bf(o[d0][1] * inv);
      w.z = bf(o[d0][2] * inv); w.w = bf(o[d0][3] * inv);
      *reinterpret_cast<ushort4*>(
          &ctx[(size_t)(q0 + l15)*2048 + h*64 + d0*16 + u*4]) = w;
    }
  }
}

// ---------------- launcher ----------------
extern "C" void kernel_launch(void* const* d_in, const int* in_sizes, int n_in,
                              void* d_out, int out_size, void* d_ws, size_t ws_size,
                              hipStream_t stream){
  const float* x    = (const float*)d_in[0];
  // d_in[1] = mask (unused; causal mask computed analytically)
  const float* cosp = (const float*)d_in[2];
  const float* sinp = (const float*)d_in[3];
  const float* wq   = (const float*)d_in[4];
  const float* wk   = (const float*)d_in[5];
  const float* wv   = (const float*)d_in[6];
  const float* wo   = (const float*)d_in[7];
  const float* qg   = (const float*)d_in[8];
  const float* kg   = (const float*)d_in[9];
  float* out = (float*)d_out;

  char* ws = (char*)d_ws;
  ushort* xb   = (ushort*)(ws);                    //  8 MB  x bf16
  ushort* wcat = (ushort*)(ws + 8388608);          // 12 MB  [wq;wk;wv] bf16
  ushort* wob  = (ushort*)(ws + 20971520);         //  8 MB  wo bf16
  float*  qkvf = (float* )(ws + 29360128);         // 24 MB  qkv f32 [2048][3072]
  ushort* qb   = (ushort*)(ws + 54525952);         //  8 MB  q bf16 (pre-scaled)
  ushort* kb   = (ushort*)(ws + 62914560);         //  2 MB  k bf16 [2048][512]
  ushort* vtb  = (ushort*)(ws + 65011712);         //  2 MB  v^T bf16 [512][2048] (slot-ordered)
  ushort* ctxb = (ushort*)(ws + 67108864);         //  8 MB  ctx bf16
  // total 75,497,472 bytes

  k_cvt_all<<<14336, 256, 0, stream>>>(x, wq, wk, wv, wo, xb, wcat, wob);
  k_gemm_bt<<<dim3(24, 16), 256, 0, stream>>>(xb, wcat, qkvf, 2048, 3072, 2048);
  k_normrope<<<2048, 256, 0, stream>>>(qkvf, cosp, sinp, qg, kg, qb, kb);
  k_vtrans<<<256, 256, 0, stream>>>(qkvf, vtb);
  k_attn<<<1024, 256, 0, stream>>>(qb, kb, vtb, ctxb);
  k_gemm_bt<<<dim3(16, 16), 256, 0, stream>>>(ctxb, wob, out, 2048, 2048, 2048);
}

// Round 8
// 150.461 us; speedup vs baseline: 1.1791x; 1.0002x over previous
//
#include <hip/hip_runtime.h>
#include <stdint.h>

// Problem constants (fixed-shape problem)
#define SEQ    2048
#define DMODEL 2048
#define NHEAD  32
#define NKV    8
#define HDIM   64
#define NQKV   3072   // 2048 q + 512 k + 512 v

typedef __bf16 bf16x8 __attribute__((ext_vector_type(8)));
typedef float  f32x4  __attribute__((ext_vector_type(4)));

#define SCALE2 0.180336880f   // 0.125 * log2(e): scores land in log2 domain
#define THR2   12.0f          // defer-max threshold (log2 domain); P <= 2^12

__device__ __forceinline__ ushort bf(float f){
  __bf16 h = (__bf16)f;               // native RNE convert on gfx950
  return __builtin_bit_cast(unsigned short, h);
}
__device__ __forceinline__ float b2f(ushort v){
  union { uint32_t u; float f; } a; a.u = ((uint32_t)v) << 16; return a.f;
}

__device__ __forceinline__ void gl_lds16(const void* g, void* l){
  __builtin_amdgcn_global_load_lds(
      (const __attribute__((address_space(1))) uint32_t*)g,
      (__attribute__((address_space(3))) uint32_t*)l, 16, 0, 0);
}

// ------------- all f32->bf16 converts in one kernel -------------
__global__ __launch_bounds__(256) void k_cvt_all(const float* __restrict__ x,
                                                 const float* __restrict__ wq,
                                                 const float* __restrict__ wk,
                                                 const float* __restrict__ wv,
                                                 const float* __restrict__ wo,
                                                 ushort* __restrict__ xb,
                                                 ushort* __restrict__ wcat,
                                                 ushort* __restrict__ wob){
  int i = blockIdx.x * 256 + threadIdx.x;
  const float* src; ushort* dst; int s4; int d4;
  if (i < 1048576)      { src = x;  dst = xb;   s4 = i;           d4 = s4; }
  else if (i < 2097152) { src = wq; dst = wcat; s4 = i - 1048576; d4 = s4; }
  else if (i < 2359296) { src = wk; dst = wcat; s4 = i - 2097152; d4 = s4 + 1048576; }
  else if (i < 2621440) { src = wv; dst = wcat; s4 = i - 2359296; d4 = s4 + 1310720; }
  else                  { src = wo; dst = wob;  s4 = i - 2621440; d4 = s4; }
  float4 v = reinterpret_cast<const float4*>(src)[s4];
  ushort4 o;
  o.x = bf(v.x); o.y = bf(v.y); o.z = bf(v.z); o.w = bf(v.w);
  reinterpret_cast<ushort4*>(dst)[d4] = o;
}

// ---------------- GEMM (f32 out): C = A[M][K] x B[N][K]^T ----------------
// 128x128 tile, BK=64, 4 waves (2x2). 2-PHASE pipeline: STAGE(t+1) before
// compute(t); ONE barrier per K-step. Double-buffered LDS.
__global__ __launch_bounds__(256) void k_gemm_bt(const ushort* __restrict__ A,
                                                 const ushort* __restrict__ B,
                                                 float* __restrict__ C,
                                                 int M, int N, int K){
  __shared__ ushort As[2][128*64];
  __shared__ ushort Bs[2][128*64];
  const int tid = threadIdx.x, lane = tid & 63, wid = tid >> 6;
  const int bm = blockIdx.y * 128, bn = blockIdx.x * 128;
  const int wr = wid >> 1, wc = wid & 1;
  const int l15 = lane & 15, u = lane >> 4;

  const int srow = wid*32 + (lane >> 3);
  const int scol = ((lane & 7) ^ (lane >> 3)) * 8;   // pre-swizzled k-chunk
  const ushort* Abase = A + (size_t)(bm + srow) * K + scol;
  const ushort* Bbase = B + (size_t)(bn + srow) * K + scol;

  auto STAGE = [&](int buf, int k0){
#pragma unroll
    for (int c = 0; c < 4; c++){
      gl_lds16(Abase + k0 + (size_t)c*8*K, &As[buf][(wid*32 + c*8)*64]);
      gl_lds16(Bbase + k0 + (size_t)c*8*K, &Bs[buf][(wid*32 + c*8)*64]);
    }
  };

  f32x4 acc[4][4] = {};
  const int NT = K >> 6;

  STAGE(0, 0);
  __syncthreads();

  for (int t = 0; t < NT; t++){
    const int cur = t & 1;
    if (t + 1 < NT) STAGE(cur ^ 1, (t + 1) << 6);

#pragma unroll
    for (int kc = 0; kc < 2; kc++){
      bf16x8 af[4], bfr[4];
#pragma unroll
      for (int m = 0; m < 4; m++){
        int row = wr*64 + m*16 + l15;
        af[m] = *reinterpret_cast<const bf16x8*>(&As[cur][row*64 + (((kc*4+u) ^ (row&7))*8)]);
      }
#pragma unroll
      for (int n = 0; n < 4; n++){
        int row = wc*64 + n*16 + l15;
        bfr[n] = *reinterpret_cast<const bf16x8*>(&Bs[cur][row*64 + (((kc*4+u) ^ (row&7))*8)]);
      }
      __builtin_amdgcn_s_setprio(1);
#pragma unroll
      for (int m = 0; m < 4; m++)
#pragma unroll
        for (int n = 0; n < 4; n++)
          acc[m][n] = __builtin_amdgcn_mfma_f32_16x16x32_bf16(af[m], bfr[n], acc[m][n], 0, 0, 0);
      __builtin_amdgcn_s_setprio(0);
    }

    __syncthreads();
  }

#pragma unroll
  for (int m = 0; m < 4; m++)
#pragma unroll
    for (int n = 0; n < 4; n++)
#pragma unroll
      for (int j = 0; j < 4; j++){
        int row = bm + wr*64 + m*16 + u*4 + j;
        int col = bn + wc*64 + n*16 + l15;
        C[(size_t)row * N + col] = acc[m][n][j];
      }
}

// ---------------- GEMM (bf16 out): qkvc = xb x wcat^T ----------------
// Same structure; epilogue casts to bf16 (plain convert only — no norm math).
__global__ __launch_bounds__(256) void k_gemm_btc(const ushort* __restrict__ A,
                                                  const ushort* __restrict__ B,
                                                  ushort* __restrict__ C,
                                                  int M, int N, int K){
  __shared__ ushort As[2][128*64];
  __shared__ ushort Bs[2][128*64];
  const int tid = threadIdx.x, lane = tid & 63, wid = tid >> 6;
  const int bm = blockIdx.y * 128, bn = blockIdx.x * 128;
  const int wr = wid >> 1, wc = wid & 1;
  const int l15 = lane & 15, u = lane >> 4;

  const int srow = wid*32 + (lane >> 3);
  const int scol = ((lane & 7) ^ (lane >> 3)) * 8;
  const ushort* Abase = A + (size_t)(bm + srow) * K + scol;
  const ushort* Bbase = B + (size_t)(bn + srow) * K + scol;

  auto STAGE = [&](int buf, int k0){
#pragma unroll
    for (int c = 0; c < 4; c++){
      gl_lds16(Abase + k0 + (size_t)c*8*K, &As[buf][(wid*32 + c*8)*64]);
      gl_lds16(Bbase + k0 + (size_t)c*8*K, &Bs[buf][(wid*32 + c*8)*64]);
    }
  };

  f32x4 acc[4][4] = {};
  const int NT = K >> 6;

  STAGE(0, 0);
  __syncthreads();

  for (int t = 0; t < NT; t++){
    const int cur = t & 1;
    if (t + 1 < NT) STAGE(cur ^ 1, (t + 1) << 6);

#pragma unroll
    for (int kc = 0; kc < 2; kc++){
      bf16x8 af[4], bfr[4];
#pragma unroll
      for (int m = 0; m < 4; m++){
        int row = wr*64 + m*16 + l15;
        af[m] = *reinterpret_cast<const bf16x8*>(&As[cur][row*64 + (((kc*4+u) ^ (row&7))*8)]);
      }
#pragma unroll
      for (int n = 0; n < 4; n++){
        int row = wc*64 + n*16 + l15;
        bfr[n] = *reinterpret_cast<const bf16x8*>(&Bs[cur][row*64 + (((kc*4+u) ^ (row&7))*8)]);
      }
      __builtin_amdgcn_s_setprio(1);
#pragma unroll
      for (int m = 0; m < 4; m++)
#pragma unroll
        for (int n = 0; n < 4; n++)
          acc[m][n] = __builtin_amdgcn_mfma_f32_16x16x32_bf16(af[m], bfr[n], acc[m][n], 0, 0, 0);
      __builtin_amdgcn_s_setprio(0);
    }

    __syncthreads();
  }

#pragma unroll
  for (int m = 0; m < 4; m++)
#pragma unroll
    for (int n = 0; n < 4; n++)
#pragma unroll
      for (int j = 0; j < 4; j++){
        int row = bm + wr*64 + m*16 + u*4 + j;
        int col = bn + wc*64 + n*16 + l15;
        C[(size_t)row * N + col] = bf(acc[m][n][j]);
      }
}

// ---------------- fused RMSNorm + RoPE (bf16 in, bf16 out; q, k only) -------
__global__ __launch_bounds__(256) void k_normrope(const ushort* __restrict__ qkvc,
                                                  const float* __restrict__ cosp,
                                                  const float* __restrict__ sinp,
                                                  const float* __restrict__ qg,
                                                  const float* __restrict__ kg,
                                                  ushort* __restrict__ qb,
                                                  ushort* __restrict__ kb){
  const int s = blockIdx.x;
  const int tid = threadIdx.x, lane = tid & 63, wid = tid >> 6;
  const ushort* row = qkvc + (size_t)s * NQKV;
  const float cs = cosp[s*HDIM + lane];
  const float sn = sinp[s*HDIM + lane];

  for (int hidx = wid; hidx < 40; hidx += 4){
    const bool isq = hidx < 32;
    const int col = isq ? hidx*64 : 2048 + (hidx-32)*64;
    float x = b2f(row[col + lane]);
    float ss = x * x;
#pragma unroll
    for (int m = 1; m < 64; m <<= 1) ss += __shfl_xor(ss, m);
    float r = rsqrtf(ss * (1.0f/64.0f) + 1e-6f);
    float y = x * r * (isq ? qg : kg)[lane];
    float p = __shfl_xor(y, 32);
    float out = y * cs + (lane < 32 ? -p : p) * sn;
    if (isq) qb[(size_t)s*2048 + hidx*64 + lane] = bf(out * SCALE2);
    else     kb[(size_t)s*512 + (hidx-32)*64 + lane] = bf(out);
  }
}

// ---------------- V transpose: qkvc v-section bf16 -> vtb (slot-ordered) ----
__global__ __launch_bounds__(256) void k_vtrans(const ushort* __restrict__ qkvc,
                                                ushort* __restrict__ vtb){
  __shared__ ushort tile[64][68];     // [d][s], pad 68
  const int g = blockIdx.x >> 5, st = blockIdx.x & 31;
  const int tid = threadIdx.x;
#pragma unroll
  for (int i = 0; i < 4; i++){
    int idx = i*256 + tid;
    int r = idx >> 4, c4 = idx & 15;
    ushort4 v = *reinterpret_cast<const ushort4*>(
        qkvc + (size_t)(st*64 + r)*NQKV + 2560 + g*64 + c4*4);
    tile[c4*4+0][r] = v.x;
    tile[c4*4+1][r] = v.y;
    tile[c4*4+2][r] = v.z;
    tile[c4*4+3][r] = v.w;
  }
  __syncthreads();
#pragma unroll
  for (int i = 0; i < 4; i++){
    int idx = i*256 + tid;
    int d = idx >> 4, s4 = idx & 15;
    // sigma: key chunk s4=(kb,u) -> PV-slot-ordered position
    int pos4 = (s4 >> 3)*32 + (s4 & 3)*8 + ((s4 >> 2) & 1)*4;
    ushort4 o = *reinterpret_cast<const ushort4*>(&tile[d][s4*4]);
    *reinterpret_cast<ushort4*>(vtb + (size_t)(g*64 + d)*SEQ + st*64 + pos4) = o;
  }
}

// ---------------- causal flash GQA attention (swapped QK^T, O^T) ----------
// Balanced mapping: c=bx&255 (CU stripe), s=bx>>8; g=c>>5, h=c&31;
// qt = {31-g, 16+g, 15-g, g}[s] -> every CU's 4 blocks sum to 66 tiles.
__global__ __launch_bounds__(256) void k_attn(const ushort* __restrict__ qbuf,
                                              const ushort* __restrict__ kbuf,
                                              const ushort* __restrict__ vtb,
                                              ushort* __restrict__ ctx){
  __shared__ ushort Kd[2][64*64];       // swizzled K tiles   (16 KB)
  __shared__ ushort Vd[2][64*64];       // swizzled V^T tiles (16 KB)

  const int bx = blockIdx.x;
  const int c  = bx & 255, sl = bx >> 8;
  const int cg = c >> 5,  h  = c & 31;
  const int qt = (sl == 0) ? 31 - cg : (sl == 1) ? 16 + cg
               : (sl == 2) ? 15 - cg : cg;
  const int g = h >> 2;
  const int tid = threadIdx.x, lane = tid & 63, wid = tid >> 6;
  const int l15 = lane & 15, u = lane >> 4;
  const int q0 = qt*64 + wid*16;        // wave's first q-row
  const int tmax = qt;                  // last KV tile (inclusive)

  // Q fragments (B-operand: col=l15 -> q-row)
  bf16x8 qf[2];
#pragma unroll
  for (int kc = 0; kc < 2; kc++)
    qf[kc] = *reinterpret_cast<const bf16x8*>(
        qbuf + (size_t)(q0 + l15)*2048 + h*64 + kc*32 + u*8);

  f32x4 o[4] = {};                      // O^T: o[d0][j] = O[q=l15][d0*16+u*4+j]
  float mrun = -1e30f;
  float lrun = 0.f;                     // per-lane partial (reduced at end)

  // hoisted swizzled LDS byte-offsets (loop-invariant, static-indexed)
  int koff[8], voff[8];
#pragma unroll
  for (int kb = 0; kb < 4; kb++)
#pragma unroll
    for (int kc = 0; kc < 2; kc++){
      int keyl = kb*16 + l15;
      koff[kb*2+kc] = (keyl*64 + (((kc*4+u) ^ (keyl&7))*8)) * 2;
    }
#pragma unroll
  for (int kc = 0; kc < 2; kc++)
#pragma unroll
    for (int d0 = 0; d0 < 4; d0++){
      int vrow = d0*16 + l15;
      voff[kc*4+d0] = (vrow*64 + (((kc*4+u) ^ (vrow&7))*8)) * 2;
    }

  // staging: 8 chunks of 1KB per tile; wave does 2 K + 2 V
  const int srow = wid*16 + (lane >> 3);
  const int scol = ((lane & 7) ^ (lane >> 3)) * 8;
  const ushort* ksrc0 = kbuf + (size_t)srow*512 + g*64 + scol;
  const ushort* vsrc0 = vtb  + (size_t)(g*64 + srow)*SEQ + scol;

  auto STAGE = [&](int buf, int t){
    const ushort* ks = ksrc0 + (size_t)t*64*512;
    gl_lds16(ks,         &Kd[buf][wid*1024]);
    gl_lds16(ks + 8*512, &Kd[buf][wid*1024 + 512]);
    const ushort* vs = vsrc0 + t*64;
    gl_lds16(vs,          &Vd[buf][wid*1024]);
    gl_lds16(vs + 8*SEQ,  &Vd[buf][wid*1024 + 512]);
  };

  STAGE(0, 0);
  __syncthreads();

  for (int t = 0; t <= tmax; t++){
    const int cur = t & 1;
    if (t < tmax) STAGE(cur ^ 1, t + 1);

    const char* KB = (const char*)Kd + cur*8192;
    const char* VB = (const char*)Vd + cur*8192;
    const bool full = (t*64 + 63) <= q0;

    // ---- S^T = mfma(K, Q) ----
    f32x4 st[4];
#pragma unroll
    for (int kb = 0; kb < 4; kb++){
      const int key0 = t*64 + kb*16;
      if (key0 <= q0 + 15){
        bf16x8 kf0 = *reinterpret_cast<const bf16x8*>(KB + koff[kb*2]);
        bf16x8 kf1 = *reinterpret_cast<const bf16x8*>(KB + koff[kb*2+1]);
        f32x4 a = {};
        a = __builtin_amdgcn_mfma_f32_16x16x32_bf16(kf0, qf[0], a, 0, 0, 0);
        a = __builtin_amdgcn_mfma_f32_16x16x32_bf16(kf1, qf[1], a, 0, 0, 0);
        st[kb] = a;
      } else {
        st[kb] = (f32x4){-1e30f, -1e30f, -1e30f, -1e30f};
      }
    }
    if (!full){
      const int keyb = t*64 + u*4;
      const int qr = q0 + l15;
#pragma unroll
      for (int kb = 0; kb < 4; kb++)
#pragma unroll
        for (int j = 0; j < 4; j++)
          st[kb][j] = (keyb + kb*16 + j > qr) ? -1e30f : st[kb][j];
    }

    // ---- online softmax (defer-max) ----
    {
      f32x4 mx = st[0];
#pragma unroll
      for (int kb = 1; kb < 4; kb++)
#pragma unroll
        for (int j = 0; j < 4; j++) mx[j] = fmaxf(mx[j], st[kb][j]);
      float tml = fmaxf(fmaxf(mx[0], mx[1]), fmaxf(mx[2], mx[3]));
      if (__any(tml > mrun + THR2)){
        float tm = fmaxf(tml, __shfl_xor(tml, 16));
        tm = fmaxf(tm, __shfl_xor(tm, 32));
        float mn = fmaxf(mrun, tm);
        float al = exp2f(mrun - mn);
        mrun = mn;
        lrun *= al;
#pragma unroll
        for (int d0 = 0; d0 < 4; d0++)
#pragma unroll
          for (int j = 0; j < 4; j++) o[d0][j] *= al;
      }
#pragma unroll
      for (int kb = 0; kb < 4; kb++)
#pragma unroll
        for (int j = 0; j < 4; j++){
          float p = exp2f(st[kb][j] - mrun);
          st[kb][j] = p;
          lrun += p;
        }
    }

    // ---- O^T += V^T-frag x P-frag; P packed in-lane via v_cvt_pk_bf16_f32 --
    __builtin_amdgcn_s_setprio(1);
#pragma unroll
    for (int kc = 0; kc < 2; kc++){
      union { uint32_t w[4]; bf16x8 v; } pb;
      asm("v_cvt_pk_bf16_f32 %0, %1, %2" : "=v"(pb.w[0]) : "v"(st[2*kc  ][0]), "v"(st[2*kc  ][1]));
      asm("v_cvt_pk_bf16_f32 %0, %1, %2" : "=v"(pb.w[1]) : "v"(st[2*kc  ][2]), "v"(st[2*kc  ][3]));
      asm("v_cvt_pk_bf16_f32 %0, %1, %2" : "=v"(pb.w[2]) : "v"(st[2*kc+1][0]), "v"(st[2*kc+1][1]));
      asm("v_cvt_pk_bf16_f32 %0, %1, %2" : "=v"(pb.w[3]) : "v"(st[2*kc+1][2]), "v"(st[2*kc+1][3]));
#pragma unroll
      for (int d0 = 0; d0 < 4; d0++){
        bf16x8 vb8 = *reinterpret_cast<const bf16x8*>(VB + voff[kc*4+d0]);
        o[d0] = __builtin_amdgcn_mfma_f32_16x16x32_bf16(vb8, pb.v, o[d0], 0, 0, 0);
      }
    }
    __builtin_amdgcn_s_setprio(0);

    __syncthreads();
  }

  // epilogue: reduce lrun across u-groups once; vectorized O^T store
  {
    float lt = lrun + __shfl_xor(lrun, 16);
    lt += __shfl_xor(lt, 32);
    float inv = 1.0f / lt;
#pragma unroll
    for (int d0 = 0; d0 < 4; d0++){
      ushort4 w;
      w.x = bf(o[d0][0] * inv); w.y = bf(o[d0][1] * inv);
      w.z = bf(o[d0][2] * inv); w.w = bf(o[d0][3] * inv);
      *reinterpret_cast<ushort4*>(
          &ctx[(size_t)(q0 + l15)*2048 + h*64 + d0*16 + u*4]) = w;
    }
  }
}

// ---------------- launcher ----------------
extern "C" void kernel_launch(void* const* d_in, const int* in_sizes, int n_in,
                              void* d_out, int out_size, void* d_ws, size_t ws_size,
                              hipStream_t stream){
  const float* x    = (const float*)d_in[0];
  // d_in[1] = mask (unused; causal mask computed analytically)
  const float* cosp = (const float*)d_in[2];
  const float* sinp = (const float*)d_in[3];
  const float* wq   = (const float*)d_in[4];
  const float* wk   = (const float*)d_in[5];
  const float* wv   = (const float*)d_in[6];
  const float* wo   = (const float*)d_in[7];
  const float* qg   = (const float*)d_in[8];
  const float* kg   = (const float*)d_in[9];
  float* out = (float*)d_out;

  char* ws = (char*)d_ws;
  ushort* xb   = (ushort*)(ws);                    //  8 MB  x bf16
  ushort* wcat = (ushort*)(ws + 8388608);          // 12 MB  [wq;wk;wv] bf16
  ushort* wob  = (ushort*)(ws + 20971520);         //  8 MB  wo bf16
  ushort* qkvc = (ushort*)(ws + 29360128);         // 12 MB  qkv bf16 [2048][3072]
  ushort* qb   = (ushort*)(ws + 41943040);         //  8 MB  q bf16 (pre-scaled)
  ushort* kb   = (ushort*)(ws + 50331648);         //  2 MB  k bf16 [2048][512]
  ushort* vtb  = (ushort*)(ws + 52428800);         //  2 MB  v^T bf16 (slot-ordered)
  ushort* ctxb = (ushort*)(ws + 54525952);         //  8 MB  ctx bf16
  // total 62,914,560 bytes

  k_cvt_all<<<14336, 256, 0, stream>>>(x, wq, wk, wv, wo, xb, wcat, wob);
  k_gemm_btc<<<dim3(24, 16), 256, 0, stream>>>(xb, wcat, qkvc, 2048, 3072, 2048);
  k_normrope<<<2048, 256, 0, stream>>>(qkvc, cosp, sinp, qg, kg, qb, kb);
  k_vtrans<<<256, 256, 0, stream>>>(qkvc, vtb);
  k_attn<<<1024, 256, 0, stream>>>(qb, kb, vtb, ctxb);
  k_gemm_bt<<<dim3(16, 16), 256, 0, stream>>>(ctxb, wob, out, 2048, 2048, 2048);
}